// Round 8
// baseline (653.616 us; speedup 1.0000x reference)
//
#include <hip/hip_runtime.h>
#include <hip/hip_cooperative_groups.h>

namespace cg = cooperative_groups;

// DicepolyTopk: dice loss + mean of top-10% poly1-BCE values over N=16.7M fp32.
// R12: single cooperative dispatch assembled from the measured-best parts.
// Evidence: totals 204-215us across R0/R6/R8/R11 despite pass1 going 90->50us;
// kernel sum ~125us vs wall ~210us -> ~90us lives at dispatch boundaries
// (R5 control: 1 dispatch => wall==kernel). R5's fused slowness re-diagnosed:
// it fused the UNREPLICATED u32 LDS hist (conflict counter 1.87M == R7's slow
// pass1), 512-thread blocks, branchy prefetch, idle-block select1 -- not a
// fusion problem. This kernel fuses the PROVEN components:
//  phase0 in-kernel zero (memset node gone) -> [R8 pass1 scan verbatim]
//  -> grid.sync -> [R6/R11 embedded redundant select1, all blocks]
//  -> [R11 pass2 scan verbatim, paired float4] -> grid.sync
//  -> block-0 sel2fin (R7's 256-thread variant, correctness-proven).
// Grid 1536 = 6 blocks/CU x 256 CU, compile-time (LDS 25.9KB<=26.6KB,
// launch_bounds(256,6) caps VGPR 85; components use 32-44). No polling, no
// fences, no runtime strides (R7/R9 poisons). Host falls back to the R11
// 4-dispatch path if cooperative launch is rejected.

#define NBINS 4096
#define NREP1 8
#define NREP2 4
#define G 1536                      // fused grid (co-resident by construction)
#define GT ((long long)G * 256)     // compile-time total threads
#define G1F 2048                    // fallback pass1 grid (R11)
#define G2F 1536                    // fallback pass2 grid (R11)
#define POLY_EPS 3.1f
#define LN2F 0.69314718056f

struct Ctl {
  unsigned int r;
  unsigned int pad[15];
};

// bce in log2 domain: a2=log2(p), b2=log2(1-p); bce2 = -(b2 + t*(a2-b2))
// bce = bce2*ln2 ; pt = 2^(-bce2) ; poly1 = bce + (1-pt)*eps, clamped >= 0.
__device__ __forceinline__ float poly1_val(float p, float t) {
  float a2 = __builtin_amdgcn_logf(p);         // v_log_f32: log2(p)
  float b2 = __builtin_amdgcn_logf(1.0f - p);  // log2(1-p)
  float bce2 = -(b2 + t * (a2 - b2));
  float pt = __builtin_amdgcn_exp2f(-bce2);    // v_exp_f32: 2^(-bce2)
  float v = bce2 * LN2F + (1.0f - pt) * POLY_EPS;
  return v > 0.0f ? v : 0.0f;
}

// ======================= fused single-dispatch kernel =======================
__global__ void __launch_bounds__(256, 6) fused_kernel(
    const float* __restrict__ preds, const float* __restrict__ gts,
    long long n, unsigned int K, unsigned int* __restrict__ hist1R,
    unsigned int* __restrict__ hist2R, float* __restrict__ sum2R,
    double* __restrict__ blockSums, double* __restrict__ blockSgt,
    float* __restrict__ out) {
  cg::grid_group gg = cg::this_grid();

  __shared__ unsigned lds_raw[6144];  // 24KB overlay: ph1 hist / ph2 hist+sums
  __shared__ unsigned chunk[256];
  __shared__ double wred[4][3];
  __shared__ double wredSg[4];
  __shared__ unsigned sb1, sr1;
  __shared__ double redsA[4], redsB[4], redsC[4];
  __shared__ double wfin[4][4];
  __shared__ unsigned sb2, sr2;

  const int t = threadIdx.x;
  const long long gtid = (long long)blockIdx.x * 256 + t;
  const float4* p4 = (const float4*)preds;
  const float4* t4 = (const float4*)gts;

  unsigned* hp1 = lds_raw;                  // phase1: 2 replicas x 2048 words
  unsigned* hp2 = lds_raw;                  // phase2: 2048 u16-packed words
  float* s2 = (float*)(lds_raw + 2048);     // phase2: 4096 f32 sums

  // ---- phase 0: zero global accum region (hist1R..sum2R contiguous) ----
  for (long long i = gtid; i < (long long)(NREP1 + 2 * NREP2) * NBINS; i += GT)
    hist1R[i] = 0u;
  for (int i = t; i < NBINS; i += 256) hp1[i] = 0u;
  gg.sync();  // zeroes visible everywhere before any flush

  // ---- phase 1: dice sums + L1 histogram (R8 pass1 verbatim, G=1536) ----
  {
    const unsigned rep = (unsigned)(t & 1) << 11;  // 0 or 2048
    float fI = 0.f, fSp = 0.f, fSt = 0.f;
    const long long n4 = n >> 2;
#define PROC1(pp, tt)                                          \
  do {                                                         \
    float _p = (pp), _t = (tt);                                \
    fI += _p * _t;                                             \
    fSp += _p;                                                 \
    fSt += _t;                                                 \
    float _v = poly1_val(_p, _t);                              \
    unsigned _b = __float_as_uint(_v) >> 19;                   \
    atomicAdd(&hp1[rep + (_b >> 1)], (_b & 1u) ? 0x10000u : 1u);\
  } while (0)
#define PROC1V(P, T) \
  do { PROC1(P.x, T.x); PROC1(P.y, T.y); PROC1(P.z, T.z); PROC1(P.w, T.w); } while (0)
    for (long long i = gtid; i < n4; i += 4 * GT) {
      long long i1 = i + GT, i2 = i + 2 * GT, i3 = i + 3 * GT;
      bool g1 = i1 < n4, g2 = i2 < n4, g3 = i3 < n4;
      float4 P0 = p4[i], T0 = t4[i];
      float4 P1, T1, P2, T2, P3, T3;
      if (g1) { P1 = p4[i1]; T1 = t4[i1]; }
      if (g2) { P2 = p4[i2]; T2 = t4[i2]; }
      if (g3) { P3 = p4[i3]; T3 = t4[i3]; }
      PROC1V(P0, T0);
      if (g1) PROC1V(P1, T1);
      if (g2) PROC1V(P2, T2);
      if (g3) PROC1V(P3, T3);
    }
    for (long long e = (n4 << 2) + gtid; e < n; e += GT) PROC1(preds[e], gts[e]);
#undef PROC1V
#undef PROC1
    double dI = fI, dSp = fSp, dSt = fSt;
#pragma unroll
    for (int off = 32; off; off >>= 1) {
      dI += __shfl_down(dI, off, 64);
      dSp += __shfl_down(dSp, off, 64);
      dSt += __shfl_down(dSt, off, 64);
    }
    if ((t & 63) == 0) {
      int w = t >> 6;
      wred[w][0] = dI; wred[w][1] = dSp; wred[w][2] = dSt;
    }
    __syncthreads();  // all hist atomics + wred done
    if (t == 0) {
      double a = 0, b = 0, c = 0;
#pragma unroll
      for (int w = 0; w < 4; ++w) { a += wred[w][0]; b += wred[w][1]; c += wred[w][2]; }
      blockSums[blockIdx.x * 3 + 0] = a;
      blockSums[blockIdx.x * 3 + 1] = b;
      blockSums[blockIdx.x * 3 + 2] = c;
    }
    // merge replicas+halves, flush to one of NREP1 global replica histograms
    unsigned int* dst = hist1R + (size_t)(blockIdx.x & (NREP1 - 1)) * NBINS;
    for (int i = t; i < 2048; i += 256) {
      unsigned a = hp1[i], b = hp1[i + 2048];
      unsigned c0 = (a & 0xFFFFu) + (b & 0xFFFFu);
      unsigned c1 = (a >> 16) + (b >> 16);
      if (c0) atomicAdd(&dst[2 * i + 0], c0);
      if (c1) atomicAdd(&dst[2 * i + 1], c1);
    }
  }
  gg.sync();  // hist1R complete device-wide

  // ---- select1, redundant per block (R6/R11-proven) ----
  {
    unsigned loc[16];
    unsigned tot = 0;
#pragma unroll
    for (int q = 0; q < 4; ++q) {
      uint4 acc = {0u, 0u, 0u, 0u};
      for (int r = 0; r < NREP1; ++r) {
        uint4 v = *(const uint4*)&hist1R[(size_t)r * NBINS + t * 16 + q * 4];
        acc.x += v.x; acc.y += v.y; acc.z += v.z; acc.w += v.w;
      }
      loc[q * 4 + 0] = acc.x; loc[q * 4 + 1] = acc.y;
      loc[q * 4 + 2] = acc.z; loc[q * 4 + 3] = acc.w;
      tot += acc.x + acc.y + acc.z + acc.w;
    }
    chunk[t] = tot;
    __syncthreads();
    for (int off = 1; off < 256; off <<= 1) {  // suffix scan
      unsigned add = (t + off < 256) ? chunk[t + off] : 0u;
      __syncthreads();
      chunk[t] += add;
      __syncthreads();
    }
    unsigned cum = (t < 255) ? chunk[t + 1] : 0u;
    for (int j = 15; j >= 0; --j) {
      unsigned nc = cum + loc[j];
      if (cum < K && nc >= K) {  // exactly one (t,j) globally satisfies this
        sb1 = (unsigned)(t * 16 + j);
        sr1 = K - cum;
      }
      cum = nc;
    }
  }
  // re-zero LDS overlay for phase 2
  for (int i = t; i < 2048; i += 256) hp2[i] = 0u;
  for (int i = t; i < NBINS; i += 256) s2[i] = 0.f;
  __syncthreads();  // publishes sb1/sr1 + zeroed overlay
  const unsigned b1v = sb1;

  // ---- phase 2: sum>b1 + refine in b1 (R11 pass2 verbatim, paired loads) --
  {
    double sgt = 0.0;
    const long long n8 = n >> 3;
#define PROC2(pp, tt)                                        \
  do {                                                       \
    float _v = poly1_val((pp), (tt));                        \
    unsigned _u = __float_as_uint(_v);                       \
    unsigned _b = _u >> 19;                                  \
    if (_b > b1v) {                                          \
      sgt += (double)_v;                                     \
    } else if (_b == b1v) {                                  \
      unsigned _k = (_u >> 7) & 0xFFFu;                      \
      atomicAdd(&hp2[_k >> 1], (_k & 1u) ? 0x10000u : 1u);   \
      atomicAdd(&s2[_k], _v);                                \
    }                                                        \
  } while (0)
    for (long long i = gtid; i < n8; i += GT) {
      long long j = i << 1;
      float4 pa = p4[j], pb = p4[j + 1];
      float4 ta = t4[j], tb = t4[j + 1];
      PROC2(pa.x, ta.x); PROC2(pa.y, ta.y); PROC2(pa.z, ta.z); PROC2(pa.w, ta.w);
      PROC2(pb.x, tb.x); PROC2(pb.y, tb.y); PROC2(pb.z, tb.z); PROC2(pb.w, tb.w);
    }
    for (long long e = (n8 << 3) + gtid; e < n; e += GT) PROC2(preds[e], gts[e]);
#undef PROC2
#pragma unroll
    for (int off = 32; off; off >>= 1) sgt += __shfl_down(sgt, off, 64);
    if ((t & 63) == 0) wredSg[t >> 6] = sgt;
    __syncthreads();  // all fine-hist atomics + wredSg done
    if (t == 0)
      blockSgt[blockIdx.x] = wredSg[0] + wredSg[1] + wredSg[2] + wredSg[3];
    unsigned int* hd = hist2R + (size_t)(blockIdx.x & (NREP2 - 1)) * NBINS;
    float* sd = sum2R + (size_t)(blockIdx.x & (NREP2 - 1)) * NBINS;
    for (int i = t; i < 2048; i += 256) {
      unsigned pw = hp2[i];
      unsigned c0 = pw & 0xFFFFu, c1 = pw >> 16;
      if (c0) atomicAdd(&hd[2 * i + 0], c0);
      if (c1) atomicAdd(&hd[2 * i + 1], c1);
    }
    for (int i = t; i < NBINS; i += 256) {
      float sv = s2[i];
      if (sv != 0.f) atomicAdd(&sd[i], sv);
    }
  }
  gg.sync();  // hist2R/sum2R/blockSgt complete device-wide

  // ---- select2 + finalize: block 0 only (R7's 256-thread proven variant) --
  if (blockIdx.x != 0) return;
  {
    const unsigned K2 = sr1;  // this block's select1 remainder (>= 1)
    unsigned hl[16];
    float sl[16];
    unsigned tot = 0;
#pragma unroll
    for (int q = 0; q < 4; ++q) {
      uint4 ha = {0u, 0u, 0u, 0u};
      float4 sa = {0.f, 0.f, 0.f, 0.f};
      for (int r = 0; r < NREP2; ++r) {
        uint4 hv = *(const uint4*)&hist2R[(size_t)r * NBINS + t * 16 + q * 4];
        float4 sv = *(const float4*)&sum2R[(size_t)r * NBINS + t * 16 + q * 4];
        ha.x += hv.x; ha.y += hv.y; ha.z += hv.z; ha.w += hv.w;
        sa.x += sv.x; sa.y += sv.y; sa.z += sv.z; sa.w += sv.w;
      }
      hl[q * 4 + 0] = ha.x; hl[q * 4 + 1] = ha.y;
      hl[q * 4 + 2] = ha.z; hl[q * 4 + 3] = ha.w;
      sl[q * 4 + 0] = sa.x; sl[q * 4 + 1] = sa.y;
      sl[q * 4 + 2] = sa.z; sl[q * 4 + 3] = sa.w;
      tot += ha.x + ha.y + ha.z + ha.w;
    }
    chunk[t] = tot;
    __syncthreads();
    for (int off = 1; off < 256; off <<= 1) {
      unsigned add = (t + off < 256) ? chunk[t + off] : 0u;
      __syncthreads();
      chunk[t] += add;
      __syncthreads();
    }
    unsigned cum = (t < 255) ? chunk[t + 1] : 0u;
    for (int j = 15; j >= 0; --j) {
      unsigned nc = cum + hl[j];
      if (cum < K2 && nc >= K2) { sb2 = (unsigned)(t * 16 + j); sr2 = K2 - cum; }
      cum = nc;
    }
    __syncthreads();
    const unsigned b2 = sb2, r2 = sr2;

    double loc = 0.0, b2s = 0.0, b2c = 0.0;
#pragma unroll
    for (int j = 0; j < 16; ++j) {
      int bin = t * 16 + j;
      if (bin > (int)b2) loc += (double)sl[j];
      if (bin == (int)b2) { b2s = (double)sl[j]; b2c = (double)hl[j]; }
    }
#pragma unroll
    for (int off = 32; off; off >>= 1) {
      loc += __shfl_down(loc, off, 64);
      b2s += __shfl_down(b2s, off, 64);
      b2c += __shfl_down(b2c, off, 64);
    }
    if ((t & 63) == 0) { int w = t >> 6; redsA[w] = loc; redsB[w] = b2s; redsC[w] = b2c; }

    double I = 0, Sp = 0, St = 0, Sg = 0;
    for (int i = t; i < G; i += 256) {
      I += blockSums[i * 3 + 0];
      Sp += blockSums[i * 3 + 1];
      St += blockSums[i * 3 + 2];
      Sg += blockSgt[i];
    }
#pragma unroll
    for (int off = 32; off; off >>= 1) {
      I += __shfl_down(I, off, 64);
      Sp += __shfl_down(Sp, off, 64);
      St += __shfl_down(St, off, 64);
      Sg += __shfl_down(Sg, off, 64);
    }
    if ((t & 63) == 0) {
      int w = t >> 6;
      wfin[w][0] = I; wfin[w][1] = Sp; wfin[w][2] = St; wfin[w][3] = Sg;
    }
    __syncthreads();
    if (t == 0) {
      double S2 = 0, bs = 0, bc = 0, tI = 0, tSp = 0, tSt = 0, tSg = 0;
#pragma unroll
      for (int w = 0; w < 4; ++w) {
        S2 += redsA[w]; bs += redsB[w]; bc += redsC[w];
        tI += wfin[w][0]; tSp += wfin[w][1]; tSt += wfin[w][2]; tSg += wfin[w][3];
      }
      // ties in sub-bucket b2 span < 128 ulps: bin average for r2 remaining
      double topk_extra = S2 + (double)r2 * (bs / bc);
      double dice = 1.0 - (2.0 * tI + 1.0) / (tSp + tSt + 1.0);
      out[0] = (float)(dice + (tSg + topk_extra) / (double)K);
    }
  }
}

// ===================== fallback: R11 4-dispatch path =======================
__global__ void __launch_bounds__(256) pass1_kernel(
    const float* __restrict__ preds, const float* __restrict__ gts,
    long long n, double* __restrict__ blockSums,
    unsigned int* __restrict__ hist1R) {
  __shared__ unsigned int hp[NBINS];
  __shared__ double wred[4][3];
  const int t = threadIdx.x;
  for (int i = t; i < NBINS; i += 256) hp[i] = 0u;
  __syncthreads();
  const unsigned rep = (unsigned)(t & 1) << 11;
  float fI = 0.f, fSp = 0.f, fSt = 0.f;
  const long long n4 = n >> 2;
  const float4* p4 = (const float4*)preds;
  const float4* t4 = (const float4*)gts;
  const long long NT = (long long)G1F * 256;
  const long long gtid = (long long)blockIdx.x * 256 + t;
#define PROC1(pp, tt)                                          \
  do {                                                         \
    float _p = (pp), _t = (tt);                                \
    fI += _p * _t; fSp += _p; fSt += _t;                       \
    float _v = poly1_val(_p, _t);                              \
    unsigned _b = __float_as_uint(_v) >> 19;                   \
    atomicAdd(&hp[rep + (_b >> 1)], (_b & 1u) ? 0x10000u : 1u);\
  } while (0)
#define PROC1V(P, T) \
  do { PROC1(P.x, T.x); PROC1(P.y, T.y); PROC1(P.z, T.z); PROC1(P.w, T.w); } while (0)
  for (long long i = gtid; i < n4; i += 4 * NT) {
    long long i1 = i + NT, i2 = i + 2 * NT, i3 = i + 3 * NT;
    bool g1 = i1 < n4, g2 = i2 < n4, g3 = i3 < n4;
    float4 P0 = p4[i], T0 = t4[i];
    float4 P1, T1, P2, T2, P3, T3;
    if (g1) { P1 = p4[i1]; T1 = t4[i1]; }
    if (g2) { P2 = p4[i2]; T2 = t4[i2]; }
    if (g3) { P3 = p4[i3]; T3 = t4[i3]; }
    PROC1V(P0, T0);
    if (g1) PROC1V(P1, T1);
    if (g2) PROC1V(P2, T2);
    if (g3) PROC1V(P3, T3);
  }
  for (long long e = (n4 << 2) + gtid; e < n; e += NT) PROC1(preds[e], gts[e]);
#undef PROC1V
#undef PROC1
  double dI = fI, dSp = fSp, dSt = fSt;
#pragma unroll
  for (int off = 32; off; off >>= 1) {
    dI += __shfl_down(dI, off, 64);
    dSp += __shfl_down(dSp, off, 64);
    dSt += __shfl_down(dSt, off, 64);
  }
  if ((t & 63) == 0) { int w = t >> 6; wred[w][0] = dI; wred[w][1] = dSp; wred[w][2] = dSt; }
  __syncthreads();
  if (t == 0) {
    double a = 0, b = 0, c = 0;
#pragma unroll
    for (int w = 0; w < 4; ++w) { a += wred[w][0]; b += wred[w][1]; c += wred[w][2]; }
    blockSums[blockIdx.x * 3 + 0] = a;
    blockSums[blockIdx.x * 3 + 1] = b;
    blockSums[blockIdx.x * 3 + 2] = c;
  }
  unsigned int* dst = hist1R + (size_t)(blockIdx.x & (NREP1 - 1)) * NBINS;
  for (int i = t; i < 2048; i += 256) {
    unsigned a = hp[i], b = hp[i + 2048];
    unsigned c0 = (a & 0xFFFFu) + (b & 0xFFFFu);
    unsigned c1 = (a >> 16) + (b >> 16);
    if (c0) atomicAdd(&dst[2 * i + 0], c0);
    if (c1) atomicAdd(&dst[2 * i + 1], c1);
  }
}

__global__ void __launch_bounds__(256, 6) pass2_kernel(
    const float* __restrict__ preds, const float* __restrict__ gts,
    long long n, unsigned int K, const unsigned int* __restrict__ hist1R,
    Ctl* __restrict__ ctl, double* __restrict__ blockSgt,
    unsigned int* __restrict__ hist2R, float* __restrict__ sum2R) {
  __shared__ unsigned int hp[NBINS / 2];
  __shared__ float s[NBINS];
  __shared__ unsigned int chunk[256];
  __shared__ double wred[4];
  __shared__ unsigned int sb1;
  const int t = threadIdx.x;
  {
    unsigned loc[16];
    unsigned tot = 0;
#pragma unroll
    for (int q = 0; q < 4; ++q) {
      uint4 acc = {0u, 0u, 0u, 0u};
      for (int r = 0; r < NREP1; ++r) {
        uint4 v = *(const uint4*)&hist1R[(size_t)r * NBINS + t * 16 + q * 4];
        acc.x += v.x; acc.y += v.y; acc.z += v.z; acc.w += v.w;
      }
      loc[q * 4 + 0] = acc.x; loc[q * 4 + 1] = acc.y;
      loc[q * 4 + 2] = acc.z; loc[q * 4 + 3] = acc.w;
      tot += acc.x + acc.y + acc.z + acc.w;
    }
    chunk[t] = tot;
    __syncthreads();
    for (int off = 1; off < 256; off <<= 1) {
      unsigned add = (t + off < 256) ? chunk[t + off] : 0u;
      __syncthreads();
      chunk[t] += add;
      __syncthreads();
    }
    unsigned cum = (t < 255) ? chunk[t + 1] : 0u;
    for (int j = 15; j >= 0; --j) {
      unsigned nc = cum + loc[j];
      if (cum < K && nc >= K) { sb1 = (unsigned)(t * 16 + j); ctl->r = K - cum; }
      cum = nc;
    }
  }
  for (int i = t; i < NBINS / 2; i += 256) hp[i] = 0u;
  for (int i = t; i < NBINS; i += 256) s[i] = 0.f;
  __syncthreads();
  const unsigned b1v = sb1;
  double sgt = 0.0;
  const long long n8 = n >> 3;
  const float4* p4 = (const float4*)preds;
  const float4* t4 = (const float4*)gts;
  const long long NT = (long long)G2F * 256;
  const long long gtid = (long long)blockIdx.x * 256 + t;
#define PROC2(pp, tt)                                        \
  do {                                                       \
    float _v = poly1_val((pp), (tt));                        \
    unsigned _u = __float_as_uint(_v);                       \
    unsigned _b = _u >> 19;                                  \
    if (_b > b1v) { sgt += (double)_v; }                     \
    else if (_b == b1v) {                                    \
      unsigned _k = (_u >> 7) & 0xFFFu;                      \
      atomicAdd(&hp[_k >> 1], (_k & 1u) ? 0x10000u : 1u);    \
      atomicAdd(&s[_k], _v);                                 \
    }                                                        \
  } while (0)
  for (long long i = gtid; i < n8; i += NT) {
    long long j = i << 1;
    float4 pa = p4[j], pb = p4[j + 1];
    float4 ta = t4[j], tb = t4[j + 1];
    PROC2(pa.x, ta.x); PROC2(pa.y, ta.y); PROC2(pa.z, ta.z); PROC2(pa.w, ta.w);
    PROC2(pb.x, tb.x); PROC2(pb.y, tb.y); PROC2(pb.z, tb.z); PROC2(pb.w, tb.w);
  }
  for (long long e = (n8 << 3) + gtid; e < n; e += NT) PROC2(preds[e], gts[e]);
#undef PROC2
#pragma unroll
  for (int off = 32; off; off >>= 1) sgt += __shfl_down(sgt, off, 64);
  if ((t & 63) == 0) wred[t >> 6] = sgt;
  __syncthreads();
  if (t == 0) blockSgt[blockIdx.x] = wred[0] + wred[1] + wred[2] + wred[3];
  unsigned int* hd = hist2R + (size_t)(blockIdx.x & (NREP2 - 1)) * NBINS;
  float* sd = sum2R + (size_t)(blockIdx.x & (NREP2 - 1)) * NBINS;
  for (int i = t; i < NBINS / 2; i += 256) {
    unsigned pw = hp[i];
    unsigned c0 = pw & 0xFFFFu, c1 = pw >> 16;
    if (c0) atomicAdd(&hd[2 * i + 0], c0);
    if (c1) atomicAdd(&hd[2 * i + 1], c1);
  }
  for (int i = t; i < NBINS; i += 256) {
    float sv = s[i];
    if (sv != 0.f) atomicAdd(&sd[i], sv);
  }
}

__global__ void __launch_bounds__(1024) sel2fin_kernel(
    const Ctl* __restrict__ ctl, const unsigned int* __restrict__ hist2R,
    const float* __restrict__ sum2R, const double* __restrict__ blockSums,
    const double* __restrict__ blockSgt, float* __restrict__ out,
    unsigned int K) {
  __shared__ unsigned int chunk[1024];
  __shared__ double redsA[16], redsB[16], redsC[16];
  __shared__ double wfin[16][4];
  __shared__ unsigned int sb2, sr2;
  const int t = threadIdx.x;
  const unsigned K2 = ctl->r;
  unsigned hl[4];
  float sl[4];
  {
    uint4 hacc = {0u, 0u, 0u, 0u};
    float4 sacc = {0.f, 0.f, 0.f, 0.f};
    for (int r = 0; r < NREP2; ++r) {
      uint4 hv = *(const uint4*)&hist2R[(size_t)r * NBINS + t * 4];
      float4 sv = *(const float4*)&sum2R[(size_t)r * NBINS + t * 4];
      hacc.x += hv.x; hacc.y += hv.y; hacc.z += hv.z; hacc.w += hv.w;
      sacc.x += sv.x; sacc.y += sv.y; sacc.z += sv.z; sacc.w += sv.w;
    }
    hl[0] = hacc.x; hl[1] = hacc.y; hl[2] = hacc.z; hl[3] = hacc.w;
    sl[0] = sacc.x; sl[1] = sacc.y; sl[2] = sacc.z; sl[3] = sacc.w;
    chunk[t] = hacc.x + hacc.y + hacc.z + hacc.w;
  }
  __syncthreads();
  for (int off = 1; off < 1024; off <<= 1) {
    unsigned add = (t + off < 1024) ? chunk[t + off] : 0u;
    __syncthreads();
    chunk[t] += add;
    __syncthreads();
  }
  unsigned cum = (t < 1023) ? chunk[t + 1] : 0u;
  for (int j = 3; j >= 0; --j) {
    unsigned nc = cum + hl[j];
    if (cum < K2 && nc >= K2) { sb2 = (unsigned)(t * 4 + j); sr2 = K2 - cum; }
    cum = nc;
  }
  __syncthreads();
  const unsigned b2 = sb2, r2 = sr2;
  double loc = 0.0, b2s = 0.0, b2c = 0.0;
#pragma unroll
  for (int j = 0; j < 4; ++j) {
    int bin = t * 4 + j;
    if (bin > (int)b2) loc += (double)sl[j];
    if (bin == (int)b2) { b2s = (double)sl[j]; b2c = (double)hl[j]; }
  }
#pragma unroll
  for (int off = 32; off; off >>= 1) {
    loc += __shfl_down(loc, off, 64);
    b2s += __shfl_down(b2s, off, 64);
    b2c += __shfl_down(b2c, off, 64);
  }
  if ((t & 63) == 0) { int w = t >> 6; redsA[w] = loc; redsB[w] = b2s; redsC[w] = b2c; }
  double I = 0, Sp = 0, St = 0, Sg = 0;
  for (int i = t; i < G1F; i += 1024) {
    I += blockSums[i * 3 + 0];
    Sp += blockSums[i * 3 + 1];
    St += blockSums[i * 3 + 2];
  }
  for (int i = t; i < G2F; i += 1024) Sg += blockSgt[i];
#pragma unroll
  for (int off = 32; off; off >>= 1) {
    I += __shfl_down(I, off, 64);
    Sp += __shfl_down(Sp, off, 64);
    St += __shfl_down(St, off, 64);
    Sg += __shfl_down(Sg, off, 64);
  }
  if ((t & 63) == 0) {
    int w = t >> 6;
    wfin[w][0] = I; wfin[w][1] = Sp; wfin[w][2] = St; wfin[w][3] = Sg;
  }
  __syncthreads();
  if (t == 0) {
    double S2 = 0, bs = 0, bc = 0, tI = 0, tSp = 0, tSt = 0, tSg = 0;
#pragma unroll
    for (int w = 0; w < 16; ++w) {
      S2 += redsA[w]; bs += redsB[w]; bc += redsC[w];
      tI += wfin[w][0]; tSp += wfin[w][1]; tSt += wfin[w][2]; tSg += wfin[w][3];
    }
    double topk_extra = S2 + (double)r2 * (bs / bc);
    double dice = 1.0 - (2.0 * tI + 1.0) / (tSp + tSt + 1.0);
    out[0] = (float)(dice + (tSg + topk_extra) / (double)K);
  }
}

extern "C" void kernel_launch(void* const* d_in, const int* in_sizes, int n_in,
                              void* d_out, int out_size, void* d_ws,
                              size_t ws_size, hipStream_t stream) {
  (void)n_in; (void)out_size; (void)ws_size;
  const float* preds = (const float*)d_in[0];
  const float* gts = (const float*)d_in[1];
  long long n = (long long)in_sizes[0];
  unsigned int K = (unsigned int)(n * 10 / 100);  // matches int(N*10/100)
  float* outp = (float*)d_out;

  char* ws = (char*)d_ws;
  unsigned int* hist1R = (unsigned int*)ws;            // 131072 (zeroed in-kernel)
  unsigned int* hist2R = (unsigned int*)(ws + 131072); // 65536  (contiguous)
  float* sum2R = (float*)(ws + 196608);                // 65536  (contiguous)
  double* blockSums = (double*)(ws + 262144);          // 49152 (room for G1F*3)
  double* blockSgt = (double*)(ws + 311296);           // 12288
  Ctl* ctl = (Ctl*)(ws + 323584);                      // 64 (fallback only)

  void* args[] = {(void*)&preds,     (void*)&gts,    (void*)&n,
                  (void*)&K,         (void*)&hist1R, (void*)&hist2R,
                  (void*)&sum2R,     (void*)&blockSums,
                  (void*)&blockSgt,  (void*)&outp};
  if (hipLaunchCooperativeKernel((void*)fused_kernel, dim3(G), dim3(256), args,
                                 0, stream) != hipSuccess) {
    // fallback: R11's proven 4-dispatch path (~215us)
    (void)hipMemsetAsync(ws, 0, 262144, stream);
    (void)hipMemsetAsync(ctl, 0, 64, stream);
    pass1_kernel<<<G1F, 256, 0, stream>>>(preds, gts, n, blockSums, hist1R);
    pass2_kernel<<<G2F, 256, 0, stream>>>(preds, gts, n, K, hist1R, ctl,
                                          blockSgt, hist2R, sum2R);
    sel2fin_kernel<<<1, 1024, 0, stream>>>(ctl, hist2R, sum2R, blockSums,
                                           blockSgt, outp, K);
  }
}

// Round 9
// 204.709 us; speedup vs baseline: 3.1929x; 3.1929x over previous
//
#include <hip/hip_runtime.h>

// DicepolyTopk: dice loss + mean of top-10% poly1-BCE values over N=16.7M fp32.
// R13: interior-time attack under the corrected overhead model.
// Model re-fit across R0/R6/R8/R11: wall = sum(kernels) + ~88us FIXED
// (per-invocation submission/sync), per-node cost ~0 (6->4 nodes never
// helped). Fusion attempts (R5/R9/R12: cooperative, polling, grid.sync)
// all collapsed the scan loop 2-10x -> abandoned permanently.
// => only lever: kernel interiors (~120us today).
// Change: pass1 WRITES poly1 values to pv[] (67MB, float4 stores, lands in
// L3: working set 134+67=201MB < 256MB L3). pass2 reads ONLY pv: 67MB
// L3-warm + ~6 VALU/elem (was 134MB + 25-instr poly1 chain per elem,
// latency-bound at VALUBusy 21%). Bit-exact: stored float == recomputed one.
// 5 nodes (node count is free): memset -> pass1 -> select1 -> pass2 -> sel2fin.
// select1 back to its own 1-block node (removes pass2's prologue).
// Fallback via template<bool>: if ws_size can't hold pv, pass2 recomputes
// (R8-proven path). All strides compile-time; no cross-block comms.

#define NBINS 4096
#define NREP1 8
#define NREP2 4
#define G1 2048
#define G2 1536
#define POLY_EPS 3.1f
#define LN2F 0.69314718056f

struct Ctl {
  unsigned int b1;  // L1 bucket containing the k-th largest value
  unsigned int r;   // k - count(strictly greater L1 buckets)
  unsigned int pad[14];
};

// bce in log2 domain: a2=log2(p), b2=log2(1-p); bce2 = -(b2 + t*(a2-b2))
// bce = bce2*ln2 ; pt = 2^(-bce2) ; poly1 = bce + (1-pt)*eps, clamped >= 0.
__device__ __forceinline__ float poly1_val(float p, float t) {
  float a2 = __builtin_amdgcn_logf(p);         // v_log_f32: log2(p)
  float b2 = __builtin_amdgcn_logf(1.0f - p);  // log2(1-p)
  float bce2 = -(b2 + t * (a2 - b2));
  float pt = __builtin_amdgcn_exp2f(-bce2);    // v_exp_f32: 2^(-bce2)
  float v = bce2 * LN2F + (1.0f - pt) * POLY_EPS;
  return v > 0.0f ? v : 0.0f;
}

// ------- pass 1: dice sums + L1 histogram (+ optional poly1 writeback) -----
template <bool WRITEPV>
__global__ void __launch_bounds__(256) pass1_kernel(
    const float* __restrict__ preds, const float* __restrict__ gts,
    long long n, double* __restrict__ blockSums,
    unsigned int* __restrict__ hist1R, float* __restrict__ pv) {
  // 2 replicas (lane parity) x 2048 words; word = replica*2048 + (bin>>1),
  // halfword = bin&1. 16KB total. Per-block elems 8192 < 65535: no overflow.
  __shared__ unsigned int hp[NBINS];
  __shared__ double wred[4][3];
  const int t = threadIdx.x;
  for (int i = t; i < NBINS; i += 256) hp[i] = 0u;
  __syncthreads();
  const unsigned rep = (unsigned)(t & 1) << 11;  // 0 or 2048

  float fI = 0.f, fSp = 0.f, fSt = 0.f;
  const long long n4 = n >> 2;
  const float4* p4 = (const float4*)preds;
  const float4* t4 = (const float4*)gts;
  float4* pv4 = (float4*)pv;
  const long long NT = (long long)G1 * 256;  // compile-time stride
  const long long gtid = (long long)blockIdx.x * 256 + t;

#define PROC1(pp, tt, vo)                                      \
  do {                                                         \
    float _p = (pp), _t = (tt);                                \
    fI += _p * _t;                                             \
    fSp += _p;                                                 \
    fSt += _t;                                                 \
    float _v = poly1_val(_p, _t);                              \
    (vo) = _v;                                                 \
    unsigned _b = __float_as_uint(_v) >> 19;                   \
    atomicAdd(&hp[rep + (_b >> 1)], (_b & 1u) ? 0x10000u : 1u);\
  } while (0)
#define PROC1V(P, T, I)                                        \
  do {                                                         \
    float4 _o;                                                 \
    PROC1(P.x, T.x, _o.x);                                     \
    PROC1(P.y, T.y, _o.y);                                     \
    PROC1(P.z, T.z, _o.z);                                     \
    PROC1(P.w, T.w, _o.w);                                     \
    if (WRITEPV) pv4[I] = _o;                                  \
  } while (0)

  for (long long i = gtid; i < n4; i += 4 * NT) {
    long long i1 = i + NT, i2 = i + 2 * NT, i3 = i + 3 * NT;
    bool g1 = i1 < n4, g2 = i2 < n4, g3 = i3 < n4;
    float4 P0 = p4[i], T0 = t4[i];
    float4 P1, T1, P2, T2, P3, T3;
    if (g1) { P1 = p4[i1]; T1 = t4[i1]; }
    if (g2) { P2 = p4[i2]; T2 = t4[i2]; }
    if (g3) { P3 = p4[i3]; T3 = t4[i3]; }
    PROC1V(P0, T0, i);
    if (g1) PROC1V(P1, T1, i1);
    if (g2) PROC1V(P2, T2, i2);
    if (g3) PROC1V(P3, T3, i3);
  }
  for (long long e = (n4 << 2) + gtid; e < n; e += NT) {
    float vv;
    PROC1(preds[e], gts[e], vv);
    if (WRITEPV) pv[e] = vv;
  }
#undef PROC1V
#undef PROC1

  double dI = fI, dSp = fSp, dSt = fSt;
#pragma unroll
  for (int off = 32; off; off >>= 1) {
    dI += __shfl_down(dI, off, 64);
    dSp += __shfl_down(dSp, off, 64);
    dSt += __shfl_down(dSt, off, 64);
  }
  if ((t & 63) == 0) {
    int w = t >> 6;
    wred[w][0] = dI; wred[w][1] = dSp; wred[w][2] = dSt;
  }
  __syncthreads();
  if (t == 0) {
    double a = 0, b = 0, c = 0;
#pragma unroll
    for (int w = 0; w < 4; ++w) { a += wred[w][0]; b += wred[w][1]; c += wred[w][2]; }
    blockSums[blockIdx.x * 3 + 0] = a;
    blockSums[blockIdx.x * 3 + 1] = b;
    blockSums[blockIdx.x * 3 + 2] = c;
  }

  // merge replicas+halves, flush to one of NREP1 global replica histograms
  unsigned int* dst = hist1R + (size_t)(blockIdx.x & (NREP1 - 1)) * NBINS;
  for (int i = t; i < 2048; i += 256) {
    unsigned a = hp[i], b = hp[i + 2048];
    unsigned c0 = (a & 0xFFFFu) + (b & 0xFFFFu);
    unsigned c1 = (a >> 16) + (b >> 16);
    if (c0) atomicAdd(&dst[2 * i + 0], c0);
    if (c1) atomicAdd(&dst[2 * i + 1], c1);
  }
}

// ---------------- select1: find L1 bucket of the k-th value (R8 verbatim) --
__global__ void __launch_bounds__(1024) select1_kernel(
    Ctl* ctl, const unsigned int* __restrict__ hist1R, unsigned int K) {
  __shared__ unsigned int chunk[1024];
  int t = threadIdx.x;
  unsigned hl[4];
  unsigned c = 0;
  {
    uint4 acc = {0u, 0u, 0u, 0u};
    for (int r = 0; r < NREP1; ++r) {
      uint4 v = *(const uint4*)&hist1R[(size_t)r * NBINS + t * 4];
      acc.x += v.x; acc.y += v.y; acc.z += v.z; acc.w += v.w;
    }
    hl[0] = acc.x; hl[1] = acc.y; hl[2] = acc.z; hl[3] = acc.w;
    c = acc.x + acc.y + acc.z + acc.w;
  }
  chunk[t] = c;
  __syncthreads();
  for (int off = 1; off < 1024; off <<= 1) {  // suffix scan
    unsigned add = (t + off < 1024) ? chunk[t + off] : 0u;
    __syncthreads();
    chunk[t] += add;
    __syncthreads();
  }
  unsigned cum = (t < 1023) ? chunk[t + 1] : 0u;
  for (int j = 3; j >= 0; --j) {
    unsigned nc = cum + hl[j];
    if (cum < K && nc >= K) {  // exactly one (t,j) globally satisfies this
      ctl->b1 = (unsigned)(t * 4 + j);
      ctl->r = K - cum;
    }
    cum = nc;
  }
}

// ---------------- pass 2: sum above b1 + refine within b1 ------------------
// USEPV: read precomputed poly1 values (67MB, L3-warm, ~6 VALU/elem).
// !USEPV: R8-proven recompute path (fallback when ws too small).
template <bool USEPV>
__global__ void __launch_bounds__(256, 6) pass2_kernel(
    const float* __restrict__ pv, const float* __restrict__ preds,
    const float* __restrict__ gts, long long n, const Ctl* __restrict__ ctl,
    double* __restrict__ blockSgt, unsigned int* __restrict__ hist2R,
    float* __restrict__ sum2R) {
  __shared__ unsigned int hp[NBINS / 2];  // u16-packed fine counts (8KB)
  __shared__ float s[NBINS];              // fine f32 sums (16KB)
  __shared__ double wred[4];
  const int t = threadIdx.x;

  for (int i = t; i < NBINS / 2; i += 256) hp[i] = 0u;
  for (int i = t; i < NBINS; i += 256) s[i] = 0.f;
  __syncthreads();
  const unsigned b1v = ctl->b1;

  double sgt = 0.0;
  const long long n4 = n >> 2;
  const long long NT = (long long)G2 * 256;  // compile-time stride
  const long long gtid = (long long)blockIdx.x * 256 + t;

#define PROC2(vv)                                            \
  do {                                                       \
    float _v = (vv);                                         \
    unsigned _u = __float_as_uint(_v);                       \
    unsigned _b = _u >> 19;                                  \
    if (_b > b1v) {                                          \
      sgt += (double)_v;                                     \
    } else if (_b == b1v) {                                  \
      unsigned _k = (_u >> 7) & 0xFFFu;                      \
      atomicAdd(&hp[_k >> 1], (_k & 1u) ? 0x10000u : 1u);    \
      atomicAdd(&s[_k], _v);                                 \
    }                                                        \
  } while (0)

  if (USEPV) {
    const float4* v4 = (const float4*)pv;
    for (long long i = gtid; i < n4; i += 4 * NT) {
      long long i1 = i + NT, i2 = i + 2 * NT, i3 = i + 3 * NT;
      bool g1 = i1 < n4, g2 = i2 < n4, g3 = i3 < n4;
      float4 V0 = v4[i];
      float4 V1, V2, V3;
      if (g1) V1 = v4[i1];
      if (g2) V2 = v4[i2];
      if (g3) V3 = v4[i3];
      PROC2(V0.x); PROC2(V0.y); PROC2(V0.z); PROC2(V0.w);
      if (g1) { PROC2(V1.x); PROC2(V1.y); PROC2(V1.z); PROC2(V1.w); }
      if (g2) { PROC2(V2.x); PROC2(V2.y); PROC2(V2.z); PROC2(V2.w); }
      if (g3) { PROC2(V3.x); PROC2(V3.y); PROC2(V3.z); PROC2(V3.w); }
    }
    for (long long e = (n4 << 2) + gtid; e < n; e += NT) PROC2(pv[e]);
  } else {
    const float4* p4 = (const float4*)preds;
    const float4* t4 = (const float4*)gts;
    for (long long i = gtid; i < n4; i += 4 * NT) {
      long long i1 = i + NT, i2 = i + 2 * NT, i3 = i + 3 * NT;
      bool g1 = i1 < n4, g2 = i2 < n4, g3 = i3 < n4;
      float4 P0 = p4[i], T0 = t4[i];
      float4 P1, T1, P2, T2, P3, T3;
      if (g1) { P1 = p4[i1]; T1 = t4[i1]; }
      if (g2) { P2 = p4[i2]; T2 = t4[i2]; }
      if (g3) { P3 = p4[i3]; T3 = t4[i3]; }
      PROC2(poly1_val(P0.x, T0.x)); PROC2(poly1_val(P0.y, T0.y));
      PROC2(poly1_val(P0.z, T0.z)); PROC2(poly1_val(P0.w, T0.w));
      if (g1) {
        PROC2(poly1_val(P1.x, T1.x)); PROC2(poly1_val(P1.y, T1.y));
        PROC2(poly1_val(P1.z, T1.z)); PROC2(poly1_val(P1.w, T1.w));
      }
      if (g2) {
        PROC2(poly1_val(P2.x, T2.x)); PROC2(poly1_val(P2.y, T2.y));
        PROC2(poly1_val(P2.z, T2.z)); PROC2(poly1_val(P2.w, T2.w));
      }
      if (g3) {
        PROC2(poly1_val(P3.x, T3.x)); PROC2(poly1_val(P3.y, T3.y));
        PROC2(poly1_val(P3.z, T3.z)); PROC2(poly1_val(P3.w, T3.w));
      }
    }
    for (long long e = (n4 << 2) + gtid; e < n; e += NT)
      PROC2(poly1_val(preds[e], gts[e]));
  }
#undef PROC2

#pragma unroll
  for (int off = 32; off; off >>= 1) sgt += __shfl_down(sgt, off, 64);
  if ((t & 63) == 0) wred[t >> 6] = sgt;
  __syncthreads();
  if (t == 0) blockSgt[blockIdx.x] = wred[0] + wred[1] + wred[2] + wred[3];

  unsigned int* hd = hist2R + (size_t)(blockIdx.x & (NREP2 - 1)) * NBINS;
  float* sd = sum2R + (size_t)(blockIdx.x & (NREP2 - 1)) * NBINS;
  for (int i = t; i < NBINS / 2; i += 256) {
    unsigned pw = hp[i];
    unsigned c0 = pw & 0xFFFFu, c1 = pw >> 16;
    if (c0) atomicAdd(&hd[2 * i + 0], c0);
    if (c1) atomicAdd(&hd[2 * i + 1], c1);
  }
  for (int i = t; i < NBINS; i += 256) {
    float sv = s[i];
    if (sv != 0.f) atomicAdd(&sd[i], sv);
  }
}

// ---------------- select2 + finalize: one block (R8 verbatim) --------------
__global__ void __launch_bounds__(1024) sel2fin_kernel(
    const Ctl* __restrict__ ctl, const unsigned int* __restrict__ hist2R,
    const float* __restrict__ sum2R, const double* __restrict__ blockSums,
    const double* __restrict__ blockSgt, float* __restrict__ out,
    unsigned int K) {
  __shared__ unsigned int chunk[1024];
  __shared__ double redsA[16], redsB[16], redsC[16];
  __shared__ double wfin[16][4];
  __shared__ unsigned int sb2, sr2;
  const int t = threadIdx.x;
  const unsigned K2 = ctl->r;  // remaining count needed from bucket b1 (>= 1)

  unsigned hl[4];
  float sl[4];
  {
    uint4 hacc = {0u, 0u, 0u, 0u};
    float4 sacc = {0.f, 0.f, 0.f, 0.f};
    for (int r = 0; r < NREP2; ++r) {
      uint4 hv = *(const uint4*)&hist2R[(size_t)r * NBINS + t * 4];
      float4 sv = *(const float4*)&sum2R[(size_t)r * NBINS + t * 4];
      hacc.x += hv.x; hacc.y += hv.y; hacc.z += hv.z; hacc.w += hv.w;
      sacc.x += sv.x; sacc.y += sv.y; sacc.z += sv.z; sacc.w += sv.w;
    }
    hl[0] = hacc.x; hl[1] = hacc.y; hl[2] = hacc.z; hl[3] = hacc.w;
    sl[0] = sacc.x; sl[1] = sacc.y; sl[2] = sacc.z; sl[3] = sacc.w;
    chunk[t] = hacc.x + hacc.y + hacc.z + hacc.w;
  }
  __syncthreads();
  for (int off = 1; off < 1024; off <<= 1) {
    unsigned add = (t + off < 1024) ? chunk[t + off] : 0u;
    __syncthreads();
    chunk[t] += add;
    __syncthreads();
  }
  unsigned cum = (t < 1023) ? chunk[t + 1] : 0u;
  for (int j = 3; j >= 0; --j) {
    unsigned nc = cum + hl[j];
    if (cum < K2 && nc >= K2) { sb2 = (unsigned)(t * 4 + j); sr2 = K2 - cum; }
    cum = nc;
  }
  __syncthreads();
  const unsigned b2 = sb2, r2 = sr2;

  // exact sum of sub-buckets strictly above b2; b2's own count/sum
  double loc = 0.0, b2s = 0.0, b2c = 0.0;
#pragma unroll
  for (int j = 0; j < 4; ++j) {
    int bin = t * 4 + j;
    if (bin > (int)b2) loc += (double)sl[j];
    if (bin == (int)b2) { b2s = (double)sl[j]; b2c = (double)hl[j]; }
  }
#pragma unroll
  for (int off = 32; off; off >>= 1) {
    loc += __shfl_down(loc, off, 64);
    b2s += __shfl_down(b2s, off, 64);
    b2c += __shfl_down(b2c, off, 64);
  }
  if ((t & 63) == 0) { int w = t >> 6; redsA[w] = loc; redsB[w] = b2s; redsC[w] = b2c; }

  // ---- finalize: reduce per-block dice partials + Sgt ----
  double I = 0, Sp = 0, St = 0, Sg = 0;
  for (int i = t; i < G1; i += 1024) {
    I += blockSums[i * 3 + 0];
    Sp += blockSums[i * 3 + 1];
    St += blockSums[i * 3 + 2];
  }
  for (int i = t; i < G2; i += 1024) Sg += blockSgt[i];
#pragma unroll
  for (int off = 32; off; off >>= 1) {
    I += __shfl_down(I, off, 64);
    Sp += __shfl_down(Sp, off, 64);
    St += __shfl_down(St, off, 64);
    Sg += __shfl_down(Sg, off, 64);
  }
  if ((t & 63) == 0) {
    int w = t >> 6;
    wfin[w][0] = I; wfin[w][1] = Sp; wfin[w][2] = St; wfin[w][3] = Sg;
  }
  __syncthreads();
  if (t == 0) {
    double S2 = 0, bs = 0, bc = 0, tI = 0, tSp = 0, tSt = 0, tSg = 0;
#pragma unroll
    for (int w = 0; w < 16; ++w) {
      S2 += redsA[w]; bs += redsB[w]; bc += redsC[w];
      tI += wfin[w][0]; tSp += wfin[w][1]; tSt += wfin[w][2]; tSg += wfin[w][3];
    }
    // ties in sub-bucket b2 span < 128 ulps: bin average for the r2 remaining
    double topk_extra = S2 + (double)r2 * (bs / bc);
    double dice = 1.0 - (2.0 * tI + 1.0) / (tSp + tSt + 1.0);
    out[0] = (float)(dice + (tSg + topk_extra) / (double)K);
  }
}

extern "C" void kernel_launch(void* const* d_in, const int* in_sizes, int n_in,
                              void* d_out, int out_size, void* d_ws,
                              size_t ws_size, hipStream_t stream) {
  (void)n_in; (void)out_size;
  const float* preds = (const float*)d_in[0];
  const float* gts = (const float*)d_in[1];
  long long n = (long long)in_sizes[0];
  unsigned int K = (unsigned int)(n * 10 / 100);  // matches int(N*10/100)

  char* ws = (char*)d_ws;
  const size_t pvBytes = ((size_t)n * 4 + 255) & ~(size_t)255;
  const size_t smallBytes = 49152 + 12288 + 64 + 131072 + 65536 + 65536;
  const bool usePv = ws_size >= pvBytes + smallBytes;
  const size_t base = usePv ? pvBytes : 0;

  float* pv = (float*)ws;  // only dereferenced when usePv
  double* blockSums = (double*)(ws + base);               // G1*3*8 = 49152
  double* blockSgt = (double*)(ws + base + 49152);        // G2*8 = 12288
  Ctl* ctl = (Ctl*)(ws + base + 61440);                   // 64
  unsigned int* hist1R = (unsigned int*)(ws + base + 61504);   // 131072
  unsigned int* hist2R = (unsigned int*)(ws + base + 192576);  // 65536
  float* sum2R = (float*)(ws + base + 258112);                 // 65536

  // zero ctl + replica region (contiguous)
  (void)hipMemsetAsync(ws + base + 61440, 0, 262208, stream);

  if (usePv) {
    pass1_kernel<true><<<G1, 256, 0, stream>>>(preds, gts, n, blockSums,
                                               hist1R, pv);
    select1_kernel<<<1, 1024, 0, stream>>>(ctl, hist1R, K);
    pass2_kernel<true><<<G2, 256, 0, stream>>>(pv, preds, gts, n, ctl,
                                               blockSgt, hist2R, sum2R);
  } else {
    pass1_kernel<false><<<G1, 256, 0, stream>>>(preds, gts, n, blockSums,
                                                hist1R, pv);
    select1_kernel<<<1, 1024, 0, stream>>>(ctl, hist1R, K);
    pass2_kernel<false><<<G2, 256, 0, stream>>>(pv, preds, gts, n, ctl,
                                                blockSgt, hist2R, sum2R);
  }
  sel2fin_kernel<<<1, 1024, 0, stream>>>(ctl, hist2R, sum2R, blockSums,
                                         blockSgt, (float*)d_out, K);
}

// Round 11
// 202.024 us; speedup vs baseline: 3.2353x; 1.0133x over previous
//
#include <hip/hip_runtime.h>

// DicepolyTopk: dice loss + mean of top-10% poly1-BCE values over N=16.7M fp32.
// R15 == R14 resubmitted verbatim (R14 bench failed on container acquisition,
// not on the kernel: no compile error, no absmax, no counters; R13's identical
// structure passed). Theory under test, unchanged:
// MLP-depth fix on R13 (204.7us). R13 confirmed: wall = kernels + ~90us
// fixed; pass1=60us (201MB @ 3.3 TB/s, floor ~42), pass2<=58 (est ~40).
// Diagnosis: pass1 VGPR_Count=32 -- the `if (g1) {load}` guards split the 8
// float4 loads into separate clauses, so only ~2 loads are in flight. For
// this shape the guards are always-true (n4 % 4NT == 0) but the compiler
// can't prove it. Fix: unguarded main loop over full = n4/(4*NT) iterations
// (all 8 loads issue as one clause), guarded tail for generality. Same
// restructure for pass2's pv loop (full=2, ~1M-group guarded remainder).
// Everything else R13-verbatim. Predicted: pass1 ~45-52us (VGPR ~60-70,
// conflicts unchanged ~2.8M), pass2 ~28-35us, wall ~185-195.

#define NBINS 4096
#define NREP1 8
#define NREP2 4
#define G1 2048
#define G2 1536
#define POLY_EPS 3.1f
#define LN2F 0.69314718056f

struct Ctl {
  unsigned int b1;  // L1 bucket containing the k-th largest value
  unsigned int r;   // k - count(strictly greater L1 buckets)
  unsigned int pad[14];
};

// bce in log2 domain: a2=log2(p), b2=log2(1-p); bce2 = -(b2 + t*(a2-b2))
// bce = bce2*ln2 ; pt = 2^(-bce2) ; poly1 = bce + (1-pt)*eps, clamped >= 0.
__device__ __forceinline__ float poly1_val(float p, float t) {
  float a2 = __builtin_amdgcn_logf(p);         // v_log_f32: log2(p)
  float b2 = __builtin_amdgcn_logf(1.0f - p);  // log2(1-p)
  float bce2 = -(b2 + t * (a2 - b2));
  float pt = __builtin_amdgcn_exp2f(-bce2);    // v_exp_f32: 2^(-bce2)
  float v = bce2 * LN2F + (1.0f - pt) * POLY_EPS;
  return v > 0.0f ? v : 0.0f;
}

// ------- pass 1: dice sums + L1 histogram (+ optional poly1 writeback) -----
template <bool WRITEPV>
__global__ void __launch_bounds__(256) pass1_kernel(
    const float* __restrict__ preds, const float* __restrict__ gts,
    long long n, double* __restrict__ blockSums,
    unsigned int* __restrict__ hist1R, float* __restrict__ pv) {
  // 2 replicas (lane parity) x 2048 words; word = replica*2048 + (bin>>1),
  // halfword = bin&1. 16KB total. Per-block elems 8192 < 65535: no overflow.
  __shared__ unsigned int hp[NBINS];
  __shared__ double wred[4][3];
  const int t = threadIdx.x;
  for (int i = t; i < NBINS; i += 256) hp[i] = 0u;
  __syncthreads();
  const unsigned rep = (unsigned)(t & 1) << 11;  // 0 or 2048

  float fI = 0.f, fSp = 0.f, fSt = 0.f;
  const long long n4 = n >> 2;
  const float4* p4 = (const float4*)preds;
  const float4* t4 = (const float4*)gts;
  float4* pv4 = (float4*)pv;
  const long long NT = (long long)G1 * 256;  // compile-time stride
  const long long gtid = (long long)blockIdx.x * 256 + t;

#define PROC1(pp, tt, vo)                                      \
  do {                                                         \
    float _p = (pp), _t = (tt);                                \
    fI += _p * _t;                                             \
    fSp += _p;                                                 \
    fSt += _t;                                                 \
    float _v = poly1_val(_p, _t);                              \
    (vo) = _v;                                                 \
    unsigned _b = __float_as_uint(_v) >> 19;                   \
    atomicAdd(&hp[rep + (_b >> 1)], (_b & 1u) ? 0x10000u : 1u);\
  } while (0)
#define PROC1V(P, T, I)                                        \
  do {                                                         \
    float4 _o;                                                 \
    PROC1(P.x, T.x, _o.x);                                     \
    PROC1(P.y, T.y, _o.y);                                     \
    PROC1(P.z, T.z, _o.z);                                     \
    PROC1(P.w, T.w, _o.w);                                     \
    if (WRITEPV) pv4[I] = _o;                                  \
  } while (0)

  // ---- unguarded main loop: all 8 loads issue as one clause ----
  const long long full = n4 / (4 * NT);
  for (long long v = 0; v < full; ++v) {
    long long i = gtid + v * (4 * NT);
    long long i1 = i + NT, i2 = i + 2 * NT, i3 = i + 3 * NT;
    float4 P0 = p4[i],  T0 = t4[i];
    float4 P1 = p4[i1], T1 = t4[i1];
    float4 P2 = p4[i2], T2 = t4[i2];
    float4 P3 = p4[i3], T3 = t4[i3];
    PROC1V(P0, T0, i);
    PROC1V(P1, T1, i1);
    PROC1V(P2, T2, i2);
    PROC1V(P3, T3, i3);
  }
  // ---- guarded tail (never taken for n4 % 4NT == 0) ----
  for (long long i = gtid + full * (4 * NT); i < n4; i += NT) {
    float4 P = p4[i], T = t4[i];
    PROC1V(P, T, i);
  }
  for (long long e = (n4 << 2) + gtid; e < n; e += NT) {
    float vv;
    PROC1(preds[e], gts[e], vv);
    if (WRITEPV) pv[e] = vv;
  }
#undef PROC1V
#undef PROC1

  double dI = fI, dSp = fSp, dSt = fSt;
#pragma unroll
  for (int off = 32; off; off >>= 1) {
    dI += __shfl_down(dI, off, 64);
    dSp += __shfl_down(dSp, off, 64);
    dSt += __shfl_down(dSt, off, 64);
  }
  if ((t & 63) == 0) {
    int w = t >> 6;
    wred[w][0] = dI; wred[w][1] = dSp; wred[w][2] = dSt;
  }
  __syncthreads();
  if (t == 0) {
    double a = 0, b = 0, c = 0;
#pragma unroll
    for (int w = 0; w < 4; ++w) { a += wred[w][0]; b += wred[w][1]; c += wred[w][2]; }
    blockSums[blockIdx.x * 3 + 0] = a;
    blockSums[blockIdx.x * 3 + 1] = b;
    blockSums[blockIdx.x * 3 + 2] = c;
  }

  // merge replicas+halves, flush to one of NREP1 global replica histograms
  unsigned int* dst = hist1R + (size_t)(blockIdx.x & (NREP1 - 1)) * NBINS;
  for (int i = t; i < 2048; i += 256) {
    unsigned a = hp[i], b = hp[i + 2048];
    unsigned c0 = (a & 0xFFFFu) + (b & 0xFFFFu);
    unsigned c1 = (a >> 16) + (b >> 16);
    if (c0) atomicAdd(&dst[2 * i + 0], c0);
    if (c1) atomicAdd(&dst[2 * i + 1], c1);
  }
}

// ---------------- select1: find L1 bucket of the k-th value ----------------
__global__ void __launch_bounds__(1024) select1_kernel(
    Ctl* ctl, const unsigned int* __restrict__ hist1R, unsigned int K) {
  __shared__ unsigned int chunk[1024];
  int t = threadIdx.x;
  unsigned hl[4];
  unsigned c = 0;
  {
    uint4 acc = {0u, 0u, 0u, 0u};
    for (int r = 0; r < NREP1; ++r) {
      uint4 v = *(const uint4*)&hist1R[(size_t)r * NBINS + t * 4];
      acc.x += v.x; acc.y += v.y; acc.z += v.z; acc.w += v.w;
    }
    hl[0] = acc.x; hl[1] = acc.y; hl[2] = acc.z; hl[3] = acc.w;
    c = acc.x + acc.y + acc.z + acc.w;
  }
  chunk[t] = c;
  __syncthreads();
  for (int off = 1; off < 1024; off <<= 1) {  // suffix scan
    unsigned add = (t + off < 1024) ? chunk[t + off] : 0u;
    __syncthreads();
    chunk[t] += add;
    __syncthreads();
  }
  unsigned cum = (t < 1023) ? chunk[t + 1] : 0u;
  for (int j = 3; j >= 0; --j) {
    unsigned nc = cum + hl[j];
    if (cum < K && nc >= K) {  // exactly one (t,j) globally satisfies this
      ctl->b1 = (unsigned)(t * 4 + j);
      ctl->r = K - cum;
    }
    cum = nc;
  }
}

// ---------------- pass 2: sum above b1 + refine within b1 ------------------
// USEPV: read precomputed poly1 values (67MB, L3-warm, ~6 VALU/elem).
// !USEPV: R8-proven recompute path (fallback when ws too small).
template <bool USEPV>
__global__ void __launch_bounds__(256, 6) pass2_kernel(
    const float* __restrict__ pv, const float* __restrict__ preds,
    const float* __restrict__ gts, long long n, const Ctl* __restrict__ ctl,
    double* __restrict__ blockSgt, unsigned int* __restrict__ hist2R,
    float* __restrict__ sum2R) {
  __shared__ unsigned int hp[NBINS / 2];  // u16-packed fine counts (8KB)
  __shared__ float s[NBINS];              // fine f32 sums (16KB)
  __shared__ double wred[4];
  const int t = threadIdx.x;

  for (int i = t; i < NBINS / 2; i += 256) hp[i] = 0u;
  for (int i = t; i < NBINS; i += 256) s[i] = 0.f;
  __syncthreads();
  const unsigned b1v = ctl->b1;

  double sgt = 0.0;
  const long long n4 = n >> 2;
  const long long NT = (long long)G2 * 256;  // compile-time stride
  const long long gtid = (long long)blockIdx.x * 256 + t;

#define PROC2(vv)                                            \
  do {                                                       \
    float _v = (vv);                                         \
    unsigned _u = __float_as_uint(_v);                       \
    unsigned _b = _u >> 19;                                  \
    if (_b > b1v) {                                          \
      sgt += (double)_v;                                     \
    } else if (_b == b1v) {                                  \
      unsigned _k = (_u >> 7) & 0xFFFu;                      \
      atomicAdd(&hp[_k >> 1], (_k & 1u) ? 0x10000u : 1u);    \
      atomicAdd(&s[_k], _v);                                 \
    }                                                        \
  } while (0)

  if (USEPV) {
    const float4* v4 = (const float4*)pv;
    // unguarded main loop: 4 loads in one clause
    const long long full = n4 / (4 * NT);
    for (long long v = 0; v < full; ++v) {
      long long i = gtid + v * (4 * NT);
      float4 V0 = v4[i];
      float4 V1 = v4[i + NT];
      float4 V2 = v4[i + 2 * NT];
      float4 V3 = v4[i + 3 * NT];
      PROC2(V0.x); PROC2(V0.y); PROC2(V0.z); PROC2(V0.w);
      PROC2(V1.x); PROC2(V1.y); PROC2(V1.z); PROC2(V1.w);
      PROC2(V2.x); PROC2(V2.y); PROC2(V2.z); PROC2(V2.w);
      PROC2(V3.x); PROC2(V3.y); PROC2(V3.z); PROC2(V3.w);
    }
    // guarded remainder (1M groups for this shape: 2-3 iters/thread)
    for (long long i = gtid + full * (4 * NT); i < n4; i += NT) {
      float4 V = v4[i];
      PROC2(V.x); PROC2(V.y); PROC2(V.z); PROC2(V.w);
    }
    for (long long e = (n4 << 2) + gtid; e < n; e += NT) PROC2(pv[e]);
  } else {
    const float4* p4 = (const float4*)preds;
    const float4* t4 = (const float4*)gts;
    for (long long i = gtid; i < n4; i += NT) {
      long long j = i;
      float4 P = p4[j], T = t4[j];
      PROC2(poly1_val(P.x, T.x)); PROC2(poly1_val(P.y, T.y));
      PROC2(poly1_val(P.z, T.z)); PROC2(poly1_val(P.w, T.w));
    }
    for (long long e = (n4 << 2) + gtid; e < n; e += NT)
      PROC2(poly1_val(preds[e], gts[e]));
  }
#undef PROC2

#pragma unroll
  for (int off = 32; off; off >>= 1) sgt += __shfl_down(sgt, off, 64);
  if ((t & 63) == 0) wred[t >> 6] = sgt;
  __syncthreads();
  if (t == 0) blockSgt[blockIdx.x] = wred[0] + wred[1] + wred[2] + wred[3];

  unsigned int* hd = hist2R + (size_t)(blockIdx.x & (NREP2 - 1)) * NBINS;
  float* sd = sum2R + (size_t)(blockIdx.x & (NREP2 - 1)) * NBINS;
  for (int i = t; i < NBINS / 2; i += 256) {
    unsigned pw = hp[i];
    unsigned c0 = pw & 0xFFFFu, c1 = pw >> 16;
    if (c0) atomicAdd(&hd[2 * i + 0], c0);
    if (c1) atomicAdd(&hd[2 * i + 1], c1);
  }
  for (int i = t; i < NBINS; i += 256) {
    float sv = s[i];
    if (sv != 0.f) atomicAdd(&sd[i], sv);
  }
}

// ---------------- select2 + finalize: one block ----------------------------
__global__ void __launch_bounds__(1024) sel2fin_kernel(
    const Ctl* __restrict__ ctl, const unsigned int* __restrict__ hist2R,
    const float* __restrict__ sum2R, const double* __restrict__ blockSums,
    const double* __restrict__ blockSgt, float* __restrict__ out,
    unsigned int K) {
  __shared__ unsigned int chunk[1024];
  __shared__ double redsA[16], redsB[16], redsC[16];
  __shared__ double wfin[16][4];
  __shared__ unsigned int sb2, sr2;
  const int t = threadIdx.x;
  const unsigned K2 = ctl->r;  // remaining count needed from bucket b1 (>= 1)

  unsigned hl[4];
  float sl[4];
  {
    uint4 hacc = {0u, 0u, 0u, 0u};
    float4 sacc = {0.f, 0.f, 0.f, 0.f};
    for (int r = 0; r < NREP2; ++r) {
      uint4 hv = *(const uint4*)&hist2R[(size_t)r * NBINS + t * 4];
      float4 sv = *(const float4*)&sum2R[(size_t)r * NBINS + t * 4];
      hacc.x += hv.x; hacc.y += hv.y; hacc.z += hv.z; hacc.w += hv.w;
      sacc.x += sv.x; sacc.y += sv.y; sacc.z += sv.z; sacc.w += sv.w;
    }
    hl[0] = hacc.x; hl[1] = hacc.y; hl[2] = hacc.z; hl[3] = hacc.w;
    sl[0] = sacc.x; sl[1] = sacc.y; sl[2] = sacc.z; sl[3] = sacc.w;
    chunk[t] = hacc.x + hacc.y + hacc.z + hacc.w;
  }
  __syncthreads();
  for (int off = 1; off < 1024; off <<= 1) {
    unsigned add = (t + off < 1024) ? chunk[t + off] : 0u;
    __syncthreads();
    chunk[t] += add;
    __syncthreads();
  }
  unsigned cum = (t < 1023) ? chunk[t + 1] : 0u;
  for (int j = 3; j >= 0; --j) {
    unsigned nc = cum + hl[j];
    if (cum < K2 && nc >= K2) { sb2 = (unsigned)(t * 4 + j); sr2 = K2 - cum; }
    cum = nc;
  }
  __syncthreads();
  const unsigned b2 = sb2, r2 = sr2;

  // exact sum of sub-buckets strictly above b2; b2's own count/sum
  double loc = 0.0, b2s = 0.0, b2c = 0.0;
#pragma unroll
  for (int j = 0; j < 4; ++j) {
    int bin = t * 4 + j;
    if (bin > (int)b2) loc += (double)sl[j];
    if (bin == (int)b2) { b2s = (double)sl[j]; b2c = (double)hl[j]; }
  }
#pragma unroll
  for (int off = 32; off; off >>= 1) {
    loc += __shfl_down(loc, off, 64);
    b2s += __shfl_down(b2s, off, 64);
    b2c += __shfl_down(b2c, off, 64);
  }
  if ((t & 63) == 0) { int w = t >> 6; redsA[w] = loc; redsB[w] = b2s; redsC[w] = b2c; }

  // ---- finalize: reduce per-block dice partials + Sgt ----
  double I = 0, Sp = 0, St = 0, Sg = 0;
  for (int i = t; i < G1; i += 1024) {
    I += blockSums[i * 3 + 0];
    Sp += blockSums[i * 3 + 1];
    St += blockSums[i * 3 + 2];
  }
  for (int i = t; i < G2; i += 1024) Sg += blockSgt[i];
#pragma unroll
  for (int off = 32; off; off >>= 1) {
    I += __shfl_down(I, off, 64);
    Sp += __shfl_down(Sp, off, 64);
    St += __shfl_down(St, off, 64);
    Sg += __shfl_down(Sg, off, 64);
  }
  if ((t & 63) == 0) {
    int w = t >> 6;
    wfin[w][0] = I; wfin[w][1] = Sp; wfin[w][2] = St; wfin[w][3] = Sg;
  }
  __syncthreads();
  if (t == 0) {
    double S2 = 0, bs = 0, bc = 0, tI = 0, tSp = 0, tSt = 0, tSg = 0;
#pragma unroll
    for (int w = 0; w < 16; ++w) {
      S2 += redsA[w]; bs += redsB[w]; bc += redsC[w];
      tI += wfin[w][0]; tSp += wfin[w][1]; tSt += wfin[w][2]; tSg += wfin[w][3];
    }
    // ties in sub-bucket b2 span < 128 ulps: bin average for the r2 remaining
    double topk_extra = S2 + (double)r2 * (bs / bc);
    double dice = 1.0 - (2.0 * tI + 1.0) / (tSp + tSt + 1.0);
    out[0] = (float)(dice + (tSg + topk_extra) / (double)K);
  }
}

extern "C" void kernel_launch(void* const* d_in, const int* in_sizes, int n_in,
                              void* d_out, int out_size, void* d_ws,
                              size_t ws_size, hipStream_t stream) {
  (void)n_in; (void)out_size;
  const float* preds = (const float*)d_in[0];
  const float* gts = (const float*)d_in[1];
  long long n = (long long)in_sizes[0];
  unsigned int K = (unsigned int)(n * 10 / 100);  // matches int(N*10/100)

  char* ws = (char*)d_ws;
  const size_t pvBytes = ((size_t)n * 4 + 255) & ~(size_t)255;
  const size_t smallBytes = 49152 + 12288 + 64 + 131072 + 65536 + 65536;
  const bool usePv = ws_size >= pvBytes + smallBytes;
  const size_t base = usePv ? pvBytes : 0;

  float* pv = (float*)ws;  // only dereferenced when usePv
  double* blockSums = (double*)(ws + base);               // G1*3*8 = 49152
  double* blockSgt = (double*)(ws + base + 49152);        // G2*8 = 12288
  Ctl* ctl = (Ctl*)(ws + base + 61440);                   // 64
  unsigned int* hist1R = (unsigned int*)(ws + base + 61504);   // 131072
  unsigned int* hist2R = (unsigned int*)(ws + base + 192576);  // 65536
  float* sum2R = (float*)(ws + base + 258112);                 // 65536

  // zero ctl + replica region (contiguous)
  (void)hipMemsetAsync(ws + base + 61440, 0, 262208, stream);

  if (usePv) {
    pass1_kernel<true><<<G1, 256, 0, stream>>>(preds, gts, n, blockSums,
                                               hist1R, pv);
    select1_kernel<<<1, 1024, 0, stream>>>(ctl, hist1R, K);
    pass2_kernel<true><<<G2, 256, 0, stream>>>(pv, preds, gts, n, ctl,
                                               blockSgt, hist2R, sum2R);
  } else {
    pass1_kernel<false><<<G1, 256, 0, stream>>>(preds, gts, n, blockSums,
                                                hist1R, pv);
    select1_kernel<<<1, 1024, 0, stream>>>(ctl, hist1R, K);
    pass2_kernel<false><<<G2, 256, 0, stream>>>(pv, preds, gts, n, ctl,
                                                blockSgt, hist2R, sum2R);
  }
  sel2fin_kernel<<<1, 1024, 0, stream>>>(ctl, hist2R, sum2R, blockSums,
                                         blockSgt, (float*)d_out, K);
}